// Round 11
// baseline (765.397 us; speedup 1.0000x reference)
//
#include <hip/hip_runtime.h>

#define NPTS 16384   // B*N = 8*2048
#define NB 2048
#define KNN 20

typedef __attribute__((ext_vector_type(4))) float f32x4;
typedef __attribute__((ext_vector_type(8))) short short8;

union U4S8 { uint4 q; short8 s; };
union W4   { unsigned u[4]; short8 s; };

__device__ __forceinline__ unsigned bf16_rne(float v){
    unsigned u = __float_as_uint(v);
    return (u + 0x7fffu + ((u>>16)&1u)) >> 16;
}
// hw pack: low16 = bf16_rne(a), high16 = bf16_rne(b)
__device__ __forceinline__ unsigned cvt_pk_bf16(float a, float b){
    unsigned r;
    asm("v_cvt_pk_bf16_f32 %0, %1, %2" : "=v"(r) : "v"(a), "v"(b));
    return r;
}
// pack fp32 -> (hi bf16) | (lo bf16 << 16), hi+lo ~= v to ~2^-17 rel (value-identical to old bit-math)
__device__ __forceinline__ unsigned pack_hl(float v){
    unsigned h = cvt_pk_bf16(v, v);
    float r = v - __uint_as_float(h << 16);
    unsigned l = cvt_pk_bf16(r, r);
    return __builtin_amdgcn_perm(l, h, 0x05040100u);   // [h.b0,h.b1,l.b0,l.b1]
}
// pack a PAIR: h2 = hi(v0)|hi(v1)<<16, l2 = lo(v0)|lo(v1)<<16
__device__ __forceinline__ void pack2(float v0, float v1, unsigned& h2, unsigned& l2){
    h2 = cvt_pk_bf16(v0, v1);
    float r0 = v0 - __uint_as_float(h2 << 16);
    float r1 = v1 - __uint_as_float(h2 & 0xffff0000u);
    l2 = cvt_pk_bf16(r0, r1);
}
// split 8 packed (hi|lo<<16) words into hi/lo bf16x8 fragments
__device__ __forceinline__ void split_hl(uint4 w0, uint4 w1, short8& hi, short8& lo){
    W4 h, l;
    h.u[0] = __builtin_amdgcn_perm(w0.y, w0.x, 0x05040100u);
    l.u[0] = __builtin_amdgcn_perm(w0.y, w0.x, 0x07060302u);
    h.u[1] = __builtin_amdgcn_perm(w0.w, w0.z, 0x05040100u);
    l.u[1] = __builtin_amdgcn_perm(w0.w, w0.z, 0x07060302u);
    h.u[2] = __builtin_amdgcn_perm(w1.y, w1.x, 0x05040100u);
    l.u[2] = __builtin_amdgcn_perm(w1.y, w1.x, 0x07060302u);
    h.u[3] = __builtin_amdgcn_perm(w1.w, w1.z, 0x05040100u);
    l.u[3] = __builtin_amdgcn_perm(w1.w, w1.z, 0x07060302u);
    hi = h.s; lo = l.s;
}
// fp32-like product via 3 bf16 MFMAs (fixed order -> deterministic across kernels)
__device__ __forceinline__ f32x4 e3_mfma(short8 Ah, short8 Al, short8 Bh, short8 Bl){
    f32x4 acc = (f32x4){0.f,0.f,0.f,0.f};
    acc = __builtin_amdgcn_mfma_f32_16x16x32_bf16(Al, Bh, acc, 0,0,0);
    acc = __builtin_amdgcn_mfma_f32_16x16x32_bf16(Ah, Bl, acc, 0,0,0);
    acc = __builtin_amdgcn_mfma_f32_16x16x32_bf16(Ah, Bh, acc, 0,0,0);
    return acc;
}

// ---------------- merged prep: pack_bfrag (3x) + 6x transpose128 + 1x transpose32 ----------------
// Was 8 serial tiny launches (~3-5us each, launch+latency bound). One range-dispatched kernel.
__global__ void prep_kernel(const float* w0, const float* w1, const float* w2, unsigned short* wpk,
                            const float* wq, const float* wk, const float* wv, const float* fc2w,
                            const float* savw, const float* satw, const float* saqk,
                            float* wqT, float* wkT, float* wvT, float* fc2T, float* savT, float* satT,
                            float* sqkT){
    int gid = blockIdx.x*256 + threadIdx.x;
    if (gid < 49152){
        int m = gid >> 14, r = gid & 16383;
        const float* W = (m==0)?w0:(m==1)?w1:w2;
        int e = r & 7, lane = (r>>3) & 63, ks = (r>>9)&3, ct = r>>11;
        int c = ct*16 + (lane&15), j = ks*32 + (lane>>4)*8 + e;
        wpk[gid] = (unsigned short)bf16_rne(W[c*128 + j]);
    } else if (gid < 147456){
        int t = gid - 49152;
        int m = t >> 14, r = t & 16383;
        const float* src = (m==0)?wq:(m==1)?wk:(m==2)?wv:(m==3)?fc2w:(m==4)?savw:satw;
        float* dst = (m==0)?wqT:(m==1)?wkT:(m==2)?wvT:(m==3)?fc2T:(m==4)?savT:satT;
        int j = r >> 7, c = r & 127;
        dst[r] = src[c*128 + j];
    } else {
        int r = gid - 147456;   // 4096 elems: sqkT[j*32+c] = saqk[c*128+j]
        int j = r >> 5, c = r & 31;
        sqkT[r] = saqk[c*128 + j];
    }
}

// ---------------- kNN ----------------
// Sortable-key argsort; see round-2 notes. Keys unique -> no tie handling.
// v2 (round 11): 16 points/block x 16 chunks of 128 candidates (was 32x8x256):
// grid 512->1024 (2->4 blocks/CU; was occupancy-limited), per-thread serial work
// halves; merge deepens to shfl_xor(1,2,4,8) within each 16-lane point group.
// Bank stagger (chunk<<1): 16 distinct banks, 4-lane broadcast -> conflict-free.
__global__ __launch_bounds__(256) void knn_kernel(const float* feat, int* g_idx){
    __shared__ float sx[2048], sy[2048], sz[2048];
    __shared__ int swin[16*20];
    int tid = threadIdx.x;
    int p0 = blockIdx.x * 16;
    int b = p0 >> 11;
    const float* fb = feat + b*3*2048;
    for (int i = tid; i < 2048; i += 256){ sx[i]=fb[i]; sy[i]=fb[2048+i]; sz[i]=fb[4096+i]; }
    __syncthreads();

    int chunk = tid & 15, pl = tid >> 4;          // 16 points/block, 16 chunks each
    int n = (p0 + pl) & 2047;
    double xi = sx[n], yi = sy[n], zi = sz[n];

    const double SENT = __longlong_as_double(0x7FE0000000000000ll);  // 2^1023, > any key
    double val[20];
#pragma unroll
    for (int k=0;k<20;k++) val[k] = SENT;

    int base = chunk*128;
    for (int ii=0; ii<128; ii++){
        int i = (ii + (chunk<<1)) & 127;
        int j = base + i;
        double dx = (double)sx[j]-xi, dy = (double)sy[j]-yi, dz = (double)sz[j]-zi;
        double d2 = dx*dx + dy*dy + dz*dz;
        long long kb = ((__double_as_longlong(d2) & ~2047ll) | (long long)j) + (1ll<<61);
        double key = __longlong_as_double(kb);
        // branchless sorted insert (ascending), dep depth 2
#pragma unroll
        for (int s=19; s>=1; s--)
            val[s] = fmax(val[s-1], fmin(val[s], key));
        val[0] = fmin(val[0], key);
    }

    // merge 16 sorted per-lane lists (consecutive lanes) via in-wave min-reduce
    for (int kk=0; kk<20; kk++){
        double h = val[0];
        h = fmin(h, __shfl_xor(h, 1));
        h = fmin(h, __shfl_xor(h, 2));
        h = fmin(h, __shfl_xor(h, 4));
        h = fmin(h, __shfl_xor(h, 8));
        if (val[0] == h){        // exactly one lane wins (keys unique; SENT never wins)
            swin[pl*20 + kk] = (int)(__double_as_longlong(h) & 2047ll);
#pragma unroll
            for (int s=0;s<19;s++) val[s] = val[s+1];
            val[19] = SENT;
        }
    }
    __syncthreads();
    for (int t = tid; t < 320; t += 256)
        g_idx[p0*20 + t] = swin[t];
}

// ---------------- x1 = xt @ fc1.T + b ----------------
__global__ void x1_kernel(const float* feat, const float* w, const float* bias, float* x1){
    int gid = blockIdx.x*256 + threadIdx.x;
    int p = gid >> 7, c = gid & 127;
    int b = p >> 11, n = p & 2047;
    const float* fb = feat + b*6144 + n;
    float v = bias[c];
    v += w[c*3+0]*fb[0];
    v += w[c*3+1]*fb[2048];
    v += w[c*3+2]*fb[4096];
    x1[gid] = v;
}

// ---------------- q/k/v ----------------
__global__ __launch_bounds__(256) void qkv_kernel(const float* x1, const float* wqT, const float* wkT,
                                                  const float* wvT, float* q, float* k1, float* v1){
    __shared__ float sx[16][128];
    int tid = threadIdx.x;
    int p0 = blockIdx.x * 16;
    for (int t = tid; t < 2048; t += 256) sx[t>>7][t&127] = x1[p0*128 + t];
    __syncthreads();
    int cg = tid & 31, pg = tid >> 5, c0 = cg*4;
    float aq[2][4] = {{0,0,0,0},{0,0,0,0}};
    float ak[2][4] = {{0,0,0,0},{0,0,0,0}};
    float av[2][4] = {{0,0,0,0},{0,0,0,0}};
    for (int j=0;j<128;j++){
        float xa = sx[pg][j], xb = sx[pg+8][j];
        float4 wq4 = *(const float4*)&wqT[j*128 + c0];
        float4 wk4 = *(const float4*)&wkT[j*128 + c0];
        float4 wv4 = *(const float4*)&wvT[j*128 + c0];
        const float* wqp = &wq4.x; const float* wkp = &wk4.x; const float* wvp = &wv4.x;
#pragma unroll
        for (int ci=0; ci<4; ci++){
            aq[0][ci] += wqp[ci]*xa; aq[1][ci] += wqp[ci]*xb;
            ak[0][ci] += wkp[ci]*xa; ak[1][ci] += wkp[ci]*xb;
            av[0][ci] += wvp[ci]*xa; av[1][ci] += wvp[ci]*xb;
        }
    }
#pragma unroll
    for (int pp=0; pp<2; pp++){
        int p = p0 + pg + pp*8;
        *(float4*)&q [p*128 + c0] = make_float4(aq[pp][0],aq[pp][1],aq[pp][2],aq[pp][3]);
        *(float4*)&k1[p*128 + c0] = make_float4(ak[pp][0],ak[pp][1],ak[pp][2],ak[pp][3]);
        *(float4*)&v1[p*128 + c0] = make_float4(av[pp][0],av[pp][1],av[pp][2],av[pp][3]);
    }
}

// ---------------- fused MFMA edge/attention kernel ----------------
// Dual-plane LDS (bufH/bufL bf16 shorts): A-frags read directly as short8.
// Round-8 epilogue kept verbatim (round-9 at->LDS staging regressed: HBM at 24%
// was not the constraint; the extra barrier+LDS round-trip added stalls).
#define ASTR 136   // shorts per row; mult of 8 (16B-aligned short8 reads)
__device__ __forceinline__ void stage_gemm(const unsigned short* bH, const unsigned short* bL,
                                           const unsigned short* wb, int lane, int ct0, f32x4 acc[5][2]){
    short8 bf[2][4];
#pragma unroll
    for (int ci=0; ci<2; ci++)
#pragma unroll
    for (int ks=0; ks<4; ks++){
        U4S8 u; u.q = *(const uint4*)(wb + ((ct0+ci)*4 + ks)*512 + lane*8);
        bf[ci][ks] = u.s;
    }
#pragma unroll
    for (int rt=0; rt<5; rt++)
#pragma unroll
    for (int ci=0; ci<2; ci++)
        acc[rt][ci] = (f32x4){0.f,0.f,0.f,0.f};
    int abase = (lane&15)*ASTR + (lane>>4)*8;
#pragma unroll
    for (int rt=0; rt<5; rt++){
#pragma unroll
        for (int ks=0; ks<4; ks++){
            int off = rt*16*ASTR + ks*32 + abase;
            short8 hi = *(const short8*)(bH + off);
            short8 lo = *(const short8*)(bL + off);
#pragma unroll
            for (int ci=0; ci<2; ci++){
                acc[rt][ci] = __builtin_amdgcn_mfma_f32_16x16x32_bf16(hi, bf[ci][ks], acc[rt][ci], 0,0,0);
                acc[rt][ci] = __builtin_amdgcn_mfma_f32_16x16x32_bf16(lo, bf[ci][ks], acc[rt][ci], 0,0,0);
            }
        }
    }
}

// store 4 packed pair-words (from acc) into the two planes at rows r0..r0+3, col
__device__ __forceinline__ void store4(unsigned short* bH, unsigned short* bL,
                                       int r0, int col, unsigned h2, unsigned l2, unsigned h3, unsigned l3){
    bH[(r0+0)*ASTR + col] = (unsigned short)h2;        bL[(r0+0)*ASTR + col] = (unsigned short)l2;
    bH[(r0+1)*ASTR + col] = (unsigned short)(h2>>16);  bL[(r0+1)*ASTR + col] = (unsigned short)(l2>>16);
    bH[(r0+2)*ASTR + col] = (unsigned short)h3;        bL[(r0+2)*ASTR + col] = (unsigned short)l3;
    bH[(r0+3)*ASTR + col] = (unsigned short)(h3>>16);  bL[(r0+3)*ASTR + col] = (unsigned short)(l3>>16);
}

__global__ __launch_bounds__(256, 3) void attn_kernel(
        const float* feat, const int* g_idx, const float* g_q, const float* g_k1, const float* g_v1,
        const unsigned short* wpk,
        const float* fb1w, const float* fb1b, const float* fb2b, const float* fg1b, const float* fg2b,
        float* g_attn, float* g_res){
    __shared__ __align__(16) unsigned short bufH[80*ASTR];   // 21760 B
    __shared__ __align__(16) unsigned short bufL[80*ASTR];   // 21760 B
    __shared__ float sh_q[512];
    __shared__ float sh_e[80*6];
    __shared__ int   sh_ix[80];
    int tid = threadIdx.x;
    int lane = tid & 63, wave = tid >> 6;
    // T1 XCD swizzle: batch == XCD id -> each XCD's L2 holds only its batch's k1/v1/q
    int bidx = blockIdx.x;
    int blk = ((bidx & 7) << 9) | (bidx >> 3);
    int gp0 = blk * 4;
    int b = gp0 >> 11;
    size_t kvbase = (size_t)b*2048*128;

    sh_q[tid]     = g_q[gp0*128 + tid];
    sh_q[tid+256] = g_q[gp0*128 + tid + 256];
    if (tid < 80){
        int r = tid;
        int nb = g_idx[gp0*20 + r];
        sh_ix[r] = nb;
        int p = (r*205) >> 12;
        int n = (gp0 & 2047) + p;
        const float* fbp = feat + b*6144;
        float cx = fbp[n], cy = fbp[2048+n], cz = fbp[4096+n];
        float nx = fbp[nb], ny = fbp[2048+nb], nz = fbp[4096+nb];
        sh_e[r*6+0] = nx-cx; sh_e[r*6+1] = ny-cy; sh_e[r*6+2] = nz-cz;
        sh_e[r*6+3] = cx;    sh_e[r*6+4] = cy;    sh_e[r*6+5] = cz;
    }
    __syncthreads();

    {
        int c = tid & 127, rh = tid >> 7;
        float w0=fb1w[c*6+0], w1=fb1w[c*6+1], w2=fb1w[c*6+2], w3=fb1w[c*6+3], w4=fb1w[c*6+4], w5=fb1w[c*6+5];
        float bb = fb1b[c];
#pragma unroll
        for (int t=0; t<20; t++){
            int r0 = t*4 + rh, r1 = r0 + 2;
            const float* e0 = &sh_e[r0*6];
            const float* e1 = &sh_e[r1*6];
            float v0 = fmaxf(bb + w0*e0[0]+w1*e0[1]+w2*e0[2]+w3*e0[3]+w4*e0[4]+w5*e0[5], 0.f);
            float v1 = fmaxf(bb + w0*e1[0]+w1*e1[1]+w2*e1[2]+w3*e1[3]+w4*e1[4]+w5*e1[5], 0.f);
            unsigned h2, l2; pack2(v0, v1, h2, l2);
            bufH[r0*ASTR + c] = (unsigned short)h2;       bufL[r0*ASTR + c] = (unsigned short)l2;
            bufH[r1*ASTR + c] = (unsigned short)(h2>>16); bufL[r1*ASTR + c] = (unsigned short)(l2>>16);
        }
    }
    __syncthreads();

    int ct0 = wave*2;
    int colA = ct0*16 + (lane&15);
    int colB = colA + 16;
    int quad = lane >> 4;
    f32x4 acc[5][2];
    float kfr[5][2][4];   // stage-1 edge features, register-resident

    stage_gemm(bufH, bufL, wpk, lane, ct0, acc);
    {
        float bA = fb2b[colA], bB = fb2b[colB];
#pragma unroll
        for (int rt=0; rt<5; rt++)
#pragma unroll
        for (int ci=0; ci<2; ci++){
            int col = ci ? colB : colA;
            float bias = ci ? bB : bA;
            float ain[4];
#pragma unroll
            for (int reg=0; reg<4; reg++){
                int row = rt*16 + quad*4 + reg;
                float kf = acc[rt][ci][reg] + bias;
                kfr[rt][ci][reg] = kf;
                int p = (row*205)>>12;
                int nb = sh_ix[row];
                float kg = g_k1[kvbase + (size_t)nb*128 + col];
                ain[reg] = sh_q[p*128 + col] - kg + kf;
            }
            unsigned h2,l2,h3,l3;
            pack2(ain[0], ain[1], h2, l2);
            pack2(ain[2], ain[3], h3, l3);
            acc[rt][ci][0] = __uint_as_float(h2); acc[rt][ci][1] = __uint_as_float(l2);
            acc[rt][ci][2] = __uint_as_float(h3); acc[rt][ci][3] = __uint_as_float(l3);
        }
    }
    __syncthreads();
#pragma unroll
    for (int rt=0; rt<5; rt++)
#pragma unroll
    for (int ci=0; ci<2; ci++)
        store4(bufH, bufL, rt*16 + quad*4, ci ? colB : colA,
               __float_as_uint(acc[rt][ci][0]), __float_as_uint(acc[rt][ci][1]),
               __float_as_uint(acc[rt][ci][2]), __float_as_uint(acc[rt][ci][3]));
    __syncthreads();

    stage_gemm(bufH, bufL, wpk + 16384, lane, ct0, acc);
    {
        float bA = fg1b[colA], bB = fg1b[colB];
#pragma unroll
        for (int rt=0; rt<5; rt++)
#pragma unroll
        for (int ci=0; ci<2; ci++){
            float bias = ci ? bB : bA;
            float v0 = fmaxf(acc[rt][ci][0] + bias, 0.f);
            float v1 = fmaxf(acc[rt][ci][1] + bias, 0.f);
            float v2 = fmaxf(acc[rt][ci][2] + bias, 0.f);
            float v3 = fmaxf(acc[rt][ci][3] + bias, 0.f);
            unsigned h2,l2,h3,l3;
            pack2(v0, v1, h2, l2);
            pack2(v2, v3, h3, l3);
            acc[rt][ci][0] = __uint_as_float(h2); acc[rt][ci][1] = __uint_as_float(l2);
            acc[rt][ci][2] = __uint_as_float(h3); acc[rt][ci][3] = __uint_as_float(l3);
        }
    }
    __syncthreads();
#pragma unroll
    for (int rt=0; rt<5; rt++)
#pragma unroll
    for (int ci=0; ci<2; ci++)
        store4(bufH, bufL, rt*16 + quad*4, ci ? colB : colA,
               __float_as_uint(acc[rt][ci][0]), __float_as_uint(acc[rt][ci][1]),
               __float_as_uint(acc[rt][ci][2]), __float_as_uint(acc[rt][ci][3]));
    __syncthreads();

    stage_gemm(bufH, bufL, wpk + 32768, lane, ct0, acc);
    // fused: bias + log-softmax(over k) in-register + at write + res accumulation.
    {
        const float SCALE = 0.08838834764831845f;
        const float NEGF  = -3e38f;
        float bA = fg2b[colA], bB = fg2b[colB];
#pragma unroll
        for (int ci=0; ci<2; ci++){
            int col = ci ? colB : colA;
            float bias = ci ? bB : bA;
            float lm[5];
#pragma unroll
            for (int rt=0; rt<5; rt++){
#pragma unroll
                for (int reg=0; reg<4; reg++)
                    acc[rt][ci][reg] = (acc[rt][ci][reg] + bias) * SCALE;
                lm[rt] = fmaxf(fmaxf(acc[rt][ci][0], acc[rt][ci][1]), fmaxf(acc[rt][ci][2], acc[rt][ci][3]));
            }
            // per-p max: p appears at rt=p (if p<=quad) and rt=p+1 (if p>=quad)
            float m[4];
#pragma unroll
            for (int j=0; j<4; j++){
                float c1 = (j<=quad) ? lm[j]   : NEGF;
                float c2 = (j>=quad) ? lm[j+1] : NEGF;
                m[j] = fmaxf(c1, c2);
                m[j] = fmaxf(m[j], __shfl_xor(m[j], 16));
                m[j] = fmaxf(m[j], __shfl_xor(m[j], 32));
            }
            // per-rt broadcast of m[p_rt]: p_rt = rt - (rt > quad)
            float mp[5];
            mp[0] = m[0];
            mp[1] = (1<=quad) ? m[1] : m[0];
            mp[2] = (2<=quad) ? m[2] : m[1];
            mp[3] = (3<=quad) ? m[3] : m[2];
            mp[4] = m[3];
            float ls[5];
#pragma unroll
            for (int rt=0; rt<5; rt++){
                float e0 = expf(acc[rt][ci][0] - mp[rt]);
                float e1 = expf(acc[rt][ci][1] - mp[rt]);
                float e2 = expf(acc[rt][ci][2] - mp[rt]);
                float e3 = expf(acc[rt][ci][3] - mp[rt]);
                ls[rt] = (e0 + e1) + (e2 + e3);
            }
            float L[4];
#pragma unroll
            for (int j=0; j<4; j++){
                float c1 = (j<=quad) ? ls[j]   : 0.f;
                float c2 = (j>=quad) ? ls[j+1] : 0.f;
                float S = c1 + c2;
                S += __shfl_xor(S, 16);
                S += __shfl_xor(S, 32);
                L[j] = m[j] + logf(S);
            }
            float Lp[5];
            Lp[0] = L[0];
            Lp[1] = (1<=quad) ? L[1] : L[0];
            Lp[2] = (2<=quad) ? L[2] : L[1];
            Lp[3] = (3<=quad) ? L[3] : L[2];
            Lp[4] = L[3];
            // at write + res partials
            float pv[5];
#pragma unroll
            for (int rt=0; rt<5; rt++){
                float pacc = 0.f;
#pragma unroll
                for (int reg=0; reg<4; reg++){
                    int row = rt*16 + quad*4 + reg;
                    float at = acc[rt][ci][reg] - Lp[rt];
                    g_attn[(size_t)(gp0*20 + row)*128 + col] = at;
                    int nb = sh_ix[row];
                    float vv = g_v1[kvbase + (size_t)nb*128 + col];
                    pacc += at * (vv + kfr[rt][ci][reg]);
                }
                pv[rt] = pacc;
            }
#pragma unroll
            for (int j=0; j<4; j++){
                float c1 = (j<=quad) ? pv[j]   : 0.f;
                float c2 = (j>=quad) ? pv[j+1] : 0.f;
                float P = c1 + c2;
                P += __shfl_xor(P, 16);
                P += __shfl_xor(P, 32);
                pv[j] = P;   // reuse: pv[0..3] now hold full res for p=j
            }
            float rv = (quad==0) ? pv[0] : (quad==1) ? pv[1] : (quad==2) ? pv[2] : pv[3];
            g_res[(size_t)(gp0 + quad)*128 + col] = rv;
        }
    }
}

// ---------------- generic per-point linear (128->128) ----------------
__global__ __launch_bounds__(256) void lin_kernel(const float* X, const float* WT, const float* bias, float* Y){
    __shared__ float sx[16][128];
    int tid = threadIdx.x;
    int p0 = blockIdx.x * 16;
    for (int t = tid; t < 2048; t += 256) sx[t>>7][t&127] = X[p0*128 + t];
    __syncthreads();
    int cg = tid & 31, pg = tid >> 5, c0 = cg*4;
    float a[2][4] = {{0,0,0,0},{0,0,0,0}};
    for (int j=0;j<128;j++){
        float xa = sx[pg][j], xb = sx[pg+8][j];
        float4 w4 = *(const float4*)&WT[j*128 + c0];
        const float* wp = &w4.x;
#pragma unroll
        for (int ci=0;ci<4;ci++){ a[0][ci] += wp[ci]*xa; a[1][ci] += wp[ci]*xb; }
    }
    float4 bv = *(const float4*)&bias[c0];
    const float* bp = &bv.x;
#pragma unroll
    for (int pp=0;pp<2;pp++){
        int p = p0 + pg + pp*8;
        *(float4*)&Y[p*128+c0] = make_float4(a[pp][0]+bp[0], a[pp][1]+bp[1], a[pp][2]+bp[2], a[pp][3]+bp[3]);
    }
}

__global__ __launch_bounds__(256) void l6_kernel(const float* Xa, const float* Xb, const float* WT,
                                                 const float* bias, float* Y){
    __shared__ float sx[16][128];
    int tid = threadIdx.x;
    int p0 = blockIdx.x * 16;
    for (int t = tid; t < 2048; t += 256) sx[t>>7][t&127] = Xa[p0*128 + t] - Xb[p0*128 + t];
    __syncthreads();
    int cg = tid & 31, pg = tid >> 5, c0 = cg*4;
    float a[2][4] = {{0,0,0,0},{0,0,0,0}};
    for (int j=0;j<128;j++){
        float xa = sx[pg][j], xb = sx[pg+8][j];
        float4 w4 = *(const float4*)&WT[j*128 + c0];
        const float* wp = &w4.x;
#pragma unroll
        for (int ci=0;ci<4;ci++){ a[0][ci] += wp[ci]*xa; a[1][ci] += wp[ci]*xb; }
    }
    float4 bv = *(const float4*)&bias[c0];
    const float* bp = &bv.x;
#pragma unroll
    for (int pp=0;pp<2;pp++){
        int p = p0 + pg + pp*8;
        *(float4*)&Y[p*128+c0] = make_float4(a[pp][0]+bp[0], a[pp][1]+bp[1], a[pp][2]+bp[2], a[pp][3]+bp[3]);
    }
}

// l5: xv = sa_v @ sres + b  -> packed hi/lo bf16, layout [b][nchunk32][c128][n32]
//     xqk = sa_qk @ sres    -> packed hi/lo bf16, layout [n][32]
__global__ __launch_bounds__(256) void l5_kernel(const float* X, const float* WvT, const float* vb,
                                                 const float* WqkT, unsigned* xvt_pk, unsigned* xqk_pk){
    __shared__ float sx[16][128];
    int tid = threadIdx.x;
    int p0 = blockIdx.x * 16;
    for (int t = tid; t < 2048; t += 256) sx[t>>7][t&127] = X[p0*128 + t];
    __syncthreads();
    int cg = tid & 31, pg = tid >> 5, c0 = cg*4;
    {
        float a[2][4] = {{0,0,0,0},{0,0,0,0}};
        for (int j=0;j<128;j++){
            float xa = sx[pg][j], xb = sx[pg+8][j];
            float4 w4 = *(const float4*)&WvT[j*128 + c0];
            const float* wp = &w4.x;
#pragma unroll
            for (int ci=0;ci<4;ci++){ a[0][ci] += wp[ci]*xa; a[1][ci] += wp[ci]*xb; }
        }
        float4 bv = *(const float4*)&vb[c0];
        const float* bp = &bv.x;
#pragma unroll
        for (int pp=0;pp<2;pp++){
            int p = p0 + pg + pp*8;
            int bb = p >> 11, n = p & 2047;
            unsigned* dst = xvt_pk + ((size_t)(bb*64 + (n>>5)))*4096 + (n&31);
#pragma unroll
            for (int ci=0;ci<4;ci++) dst[(c0+ci)*32] = pack_hl(a[pp][ci] + bp[ci]);
        }
    }
    if (cg < 8){
        int cq = cg*4;
        float a[2][4] = {{0,0,0,0},{0,0,0,0}};
        for (int j=0;j<128;j++){
            float xa = sx[pg][j], xb = sx[pg+8][j];
            float4 w4 = *(const float4*)&WqkT[j*32 + cq];
            const float* wp = &w4.x;
#pragma unroll
            for (int ci=0;ci<4;ci++){ a[0][ci] += wp[ci]*xa; a[1][ci] += wp[ci]*xb; }
        }
#pragma unroll
        for (int pp=0;pp<2;pp++){
            int p = p0 + pg + pp*8;
            uint4 w;
            w.x = pack_hl(a[pp][0]); w.y = pack_hl(a[pp][1]);
            w.z = pack_hl(a[pp][2]); w.w = pack_hl(a[pp][3]);
            *(uint4*)&xqk_pk[p*32 + cq] = w;
        }
    }
}

// ---------------- batchnorm ----------------
// v2 (round 11): grid 128 -> 512 (was 0.5 blocks/CU, half the GPU idle).
// Each block covers 32 rows; 512 atomic adds per address (acceptable tail).
__global__ void bn_stats_kernel(const float* X, float* sums){
    int tid = threadIdx.x;
    int c = tid & 127, half = tid >> 7;
    int r0 = blockIdx.x*32 + half*16;
    float s = 0.f, sq = 0.f;
    for (int r = r0; r < r0+16; r++){
        float v = X[r*128 + c];
        s += v; sq += v*v;
    }
    atomicAdd(&sums[c], s);
    atomicAdd(&sums[128+c], sq);
}

__global__ void bn1_apply_kernel(const float* res2, const float* x1, const float* sums,
                                 const float* g, const float* beta, float* sres){
    int gid = blockIdx.x*256 + threadIdx.x;
    int c = gid & 127;
    float mu = sums[c] * (1.0f/16384.f);
    float var = sums[128+c] * (1.0f/16384.f) - mu*mu;
    float inv = 1.0f / sqrtf(var + 1e-5f);
    float y = g[c]*(res2[gid]-mu)*inv + beta[c];
    sres[gid] = fmaxf(y, 0.f) + x1[gid];
}

__global__ void final_kernel(const float* sres, const float* xr2, const float* sums,
                             const float* g, const float* beta, float* out0){
    int gid = blockIdx.x*256 + threadIdx.x;
    int c = gid & 127;
    float mu = sums[c] * (1.0f/16384.f);
    float var = sums[128+c] * (1.0f/16384.f) - mu*mu;
    float inv = 1.0f / sqrtf(var + 1e-5f);
    float y = g[c]*(xr2[gid]-mu)*inv + beta[c];
    out0[gid] = sres[gid] + fmaxf(y, 0.f);
}

// ---------------- SA pass A: row max (hi-only) + exp-sum (3-product) via MFMA ----------------
// jt-loop split 4-ways across the block's waves; grid 1024 = 8 b x 128 rowgroups.
// rm exact-identical (max associative); irs reassociated 128 -> 4x32 (last-bit).
__global__ __launch_bounds__(256) void sa_stats_kernel(const unsigned* xqk_pk, float* rm, float* irs){
    __shared__ float sred[4][16];
    __shared__ float srm[16];
    int tid = threadIdx.x;
    int lane = tid & 63, wave = tid >> 6;
    int b = blockIdx.x & 7;                 // T1 XCD swizzle: batch == XCD id
    int i0 = (blockIdx.x >> 3) * 16;
    const unsigned* qb = xqk_pk + (size_t)b*2048*32;
    int quad = lane >> 4, l15 = lane & 15;
    const unsigned* ap = qb + (i0 + l15)*32 + quad*8;
    uint4 a0 = *(const uint4*)ap, a1 = *(const uint4*)(ap+4);
    short8 Ah, Al; split_hl(a0, a1, Ah, Al);

    int jt0 = wave*32;
    float m[4] = {-3e38f,-3e38f,-3e38f,-3e38f};
    for (int jt=jt0; jt<jt0+32; jt++){
        const unsigned* bp = qb + (jt*16 + l15)*32 + quad*8;
        uint4 b0 = *(const uint4*)bp, b1 = *(const uint4*)(bp+4);
        short8 Bh, Bl; split_hl(b0,b1,Bh,Bl);
        f32x4 e = (f32x4){0.f,0.f,0.f,0.f};
        e = __builtin_amdgcn_mfma_f32_16x16x32_bf16(Ah, Bh, e, 0,0,0);
#pragma unroll
        for (int r=0;r<4;r++) m[r] = fmaxf(m[r], e[r]);
    }
#pragma unroll
    for (int mk=1; mk<16; mk<<=1)
#pragma unroll
        for (int r=0;r<4;r++) m[r] = fmaxf(m[r], __shfl_xor(m[r], mk));
    if (l15 == 0){
#pragma unroll
        for (int r=0;r<4;r++) sred[wave][quad*4+r] = m[r];
    }
    __syncthreads();
    if (tid < 16)
        srm[tid] = fmaxf(fmaxf(sred[0][tid], sred[1][tid]), fmaxf(sred[2][tid], sred[3][tid]));
    __syncthreads();
    float mp[4];
#pragma unroll
    for (int r=0;r<4;r++) mp[r] = srm[quad*4+r];

    float s[4] = {0.f,0.f,0.f,0.f};
    for (int jt=jt0; jt<jt0+32; jt++){
        const unsigned* bp = qb + (jt*16 + l15)*32 + quad*8;
        uint4 b0 = *(const uint4*)bp, b1 = *(const uint4*)(bp+4);
        short8 Bh, Bl; split_hl(b0,b1,Bh,Bl);
        f32x4 e = e3_mfma(Ah,Al,Bh,Bl);
#pragma unroll
        for (int r=0;r<4;r++) s[r] += expf(e[r]-mp[r]);
    }
#pragma unroll
    for (int mk=1; mk<16; mk<<=1)
#pragma unroll
        for (int r=0;r<4;r++) s[r] += __shfl_xor(s[r], mk);
    __syncthreads();
    if (l15 == 0){
#pragma unroll
        for (int r=0;r<4;r++) sred[wave][quad*4+r] = s[r];
    }
    __syncthreads();
    if (tid < 16){
        float S = (sred[0][tid] + sred[1][tid]) + (sred[2][tid] + sred[3][tid]);
        rm[b*2048 + i0 + tid]  = srm[tid];
        irs[b*2048 + i0 + tid] = 1.0f/S;
    }
}

// ---------------- SA pass B: fused colsum + PV (flash-style), MFMA ----------------
// 4-way n-split for occupancy; NO register prefetch (round-3 spill lesson).
#define SXV_STR 36
#define ATT_STR 36
#define NSPLIT 4
__global__ __launch_bounds__(256) void sa_xr_part_kernel(const unsigned* xqk_pk, const unsigned* xvt_pk,
                                                         const float* rm, const float* irs,
                                                         float* part, float* cspart){
    __shared__ __align__(16) unsigned sxv[128*SXV_STR];   // 18432 B
    __shared__ __align__(16) unsigned attT[32*ATT_STR];   // 4608 B
    __shared__ float scs[2][2][16];
    int tid = threadIdx.x;
    int lane = tid & 63, wave = tid >> 6;
    int quad = lane >> 4, l15 = lane & 15;
    // T1 XCD swizzle: batch == XCD id (2048 = 8 x 256 blocks); within an XCD,
    // consecutive blocks share xv chunk sequence (L2 locality preserved)
    int bid = blockIdx.x;
    int b   = bid & 7;
    int rest = bid >> 3;           // 0..255
    int ns  = rest >> 6;           // 0..3
    int mt  = rest & 63;           // 0..63
    int m0 = mt*32;
    int rt = wave >> 1, ct = wave & 1;
    const unsigned* qb = xqk_pk + (size_t)b*2048*32;

    // B-frags for this block's m-cols (energy), loaded once
    short8 Bmh, Bml;
    {
        const unsigned* bp = qb + (m0 + ct*16 + l15)*32 + quad*8;
        uint4 b0 = *(const uint4*)bp, b1 = *(const uint4*)(bp+4);
        split_hl(b0,b1,Bmh,Bml);
    }
    f32x4 acc[4];
#pragma unroll
    for (int cc=0;cc<4;cc++) acc[cc] = (f32x4){0.f,0.f,0.f,0.f};
    float cs_acc = 0.f;

    int ch0 = ns*16;
    for (int ci16=0; ci16<16; ci16++){
        int chunk = ch0 + ci16;
        int n0 = chunk*32;
        __syncthreads();   // prev PV reads done
        // stage xv chunk -> LDS (packed hi/lo), [c][n] stride SXV_STR
        const unsigned* src = xvt_pk + ((size_t)(b*64 + chunk))*4096;
#pragma unroll
        for (int it=0; it<4; it++){
            int u = tid + it*256;
            int c = u >> 3, part_ = u & 7;
            *(uint4*)&sxv[c*SXV_STR + part_*4] = *(const uint4*)(src + u*4);
        }
        // energy tile (rt, ct): rows n0+rt*16.., cols m0+ct*16..
        const unsigned* ap = qb + (n0 + rt*16 + l15)*32 + quad*8;
        uint4 a0 = *(const uint4*)ap, a1 = *(const uint4*)(ap+4);
        short8 Ah, Al; split_hl(a0,a1,Ah,Al);
        f32x4 e = e3_mfma(Ah,Al,Bmh,Bml);
        // att + colsum acc + write attT (packed hi/lo)
#pragma unroll
        for (int r=0;r<4;r++){
            int rowg = b*2048 + n0 + rt*16 + quad*4 + r;
            float att = expf(e[r] - rm[rowg]) * irs[rowg];
            cs_acc += att;
            attT[(ct*16+l15)*ATT_STR + rt*16 + quad*4 + r] = pack_hl(att);
        }
        __syncthreads();
        // PV: A = att^T (m-sub = ct), B = xv (c-subs rt*4..rt*4+3)
        const unsigned* arp = attT + (ct*16+l15)*ATT_STR + quad*8;
        uint4 aa0 = *(const uint4*)arp, aa1 = *(const uint4*)(arp+4);
        short8 Aph, Apl; split_hl(aa0,aa1,Aph,Apl);
#pragma unroll
        for (int cc=0; cc<4; cc++){
            int c0 = (rt*4 + cc)*16;
            const unsigned* xp = &sxv[(c0 + l15)*SXV_STR + quad*8];
            uint4 x0 = *(const uint4*)xp, x1 = *(const uint4*)(xp+4);
            short8 Xh, Xl; split_hl(x0,x1,Xh,Xl);
            acc[cc] = __builtin_amdgcn_mfma_f32_16x16x32_bf16(Apl, Xh, acc[cc], 0,0,0);
            acc[cc] = __builtin_amdgcn_mfma_f32_16x16x32_bf16(Aph, Xl, acc[cc], 0,0,0);
            acc[cc] = __builtin_amdgcn_mfma_f32_16x16x32_bf16(Aph, Xh, acc[cc], 0,0,0);
        }
    }
    // colsum partial: reduce across quads, combine rt halves
    cs_acc += __shfl_xor(cs_acc, 16);
    cs_acc += __shfl_xor(cs_acc, 32);
    if (lane < 16) scs[ct][rt][lane] = cs_acc;
    __syncthreads();
    if (tid < 32)
        cspart[(size_t)(ns*8 + b)*2048 + m0 + tid] = scs[tid>>4][0][tid&15] + scs[tid>>4][1][tid&15];
    // unscaled partial write: row m = m0+ct*16+quad*4+r, col = (rt*4+cc)*16+l15
#pragma unroll
    for (int cc=0; cc<4; cc++){
        int c0 = (rt*4 + cc)*16;
#pragma unroll
        for (int r=0;r<4;r++){
            int mloc = ct*16 + quad*4 + r;
            part[((size_t)(ns*8 + b)*2048 + m0 + mloc)*128 + c0 + l15] = acc[cc][r];
        }
    }
}

// combine NSPLIT partials, apply column-sum normalization
__global__ void sa_combine_kernel(const float* part, const float* cspart, float* xr){
    int gid = blockIdx.x*256 + threadIdx.x;   // 2M elements: (b*2048+m)*128+c
    int bm = gid >> 7;
    float cs = cspart[bm] + cspart[bm+16384] + cspart[bm+2*16384] + cspart[bm+3*16384];
    float v  = part[gid] + part[gid+2097152] + part[gid+2*2097152] + part[gid+3*2097152];
    xr[gid] = v * (1.0f/(1e-9f + cs));
}

// ---------------- launch ----------------
extern "C" void kernel_launch(void* const* d_in, const int* in_sizes, int n_in,
                              void* d_out, int out_size, void* d_ws, size_t ws_size,
                              hipStream_t stream){
    (void)in_sizes; (void)n_in; (void)out_size; (void)ws_size;
    const float* feat = (const float*)d_in[0];
    const float* fc1w = (const float*)d_in[1];  const float* fc1b = (const float*)d_in[2];
    const float* fc2w = (const float*)d_in[3];  const float* fc2b = (const float*)d_in[4];
    const float* bng  = (const float*)d_in[5];  const float* bnb  = (const float*)d_in[6];
    const float* fb1w = (const float*)d_in[7];  const float* fb1b = (const float*)d_in[8];
    const float* fb2w = (const float*)d_in[9];  const float* fb2b = (const float*)d_in[10];
    const float* fg1w = (const float*)d_in[11]; const float* fg1b = (const float*)d_in[12];
    const float* fg2w = (const float*)d_in[13]; const float* fg2b = (const float*)d_in[14];
    const float* wq   = (const float*)d_in[15]; const float* wk   = (const float*)d_in[16];
    const float* wv   = (const float*)d_in[17];
    const float* saqk = (const float*)d_in[18];
    const float* savw = (const float*)d_in[19]; const float* savb = (const float*)d_in[20];
    const float* satw = (const float*)d_in[21]; const float* satb = (const float*)d_in[22];
    const float* sabng= (const float*)d_in[23]; const float* sabnb= (const float*)d_in[24];

    float* out0 = (float*)d_out;
    float* out1 = out0 + 2097152;

    char* ws = (char*)d_ws;
    size_t off = 0;
    auto A = [&](size_t bytes)->char*{
        char* r = ws + off;
        off = (off + bytes + 255) & ~(size_t)255;
        return r;
    };
    const size_t PBUF = (size_t)NPTS*128*4;   // 8 MB
    int*      g_idx  = (int*)A((size_t)NPTS*KNN*4);
    float*    g_x1   = (float*)A(PBUF);
    float*    g_q    = (float*)A(PBUF);
    float*    g_k1   = (float*)A(PBUF);
    float*    g_v1   = (float*)A(PBUF);
    float*    g_res  = (float*)A(PBUF);
    float*    g_res2 = (float*)A(PBUF);
    float*    g_sres = (float*)A(PBUF);
    float*    g_xr   = (float*)A(PBUF);
    float*    g_xr2  = (float*)A(PBUF);
    unsigned* g_xvt_pk = (unsigned*)A((size_t)NPTS*128*4);   // 8 MB packed
    unsigned* g_xqk_pk = (unsigned*)A((size_t)NPTS*32*4);    // 2 MB packed
    float*    g_rm   = (float*)A((size_t)NPTS*4);
    float*    g_rs   = (float*)A((size_t)NPTS*4);            // holds 1/rs
    float*    g_stats= (float*)A((size_t)512*4);             // bn1(256) bn2(256)
    unsigned short* g_wpk = (unsigned short*)A((size_t)3*16384*2);
    float*    g_wqT  = (float*)A(65536);
    float*    g_wkT  = (float*)A(65536);
    float*    g_wvT  = (float*)A(65536);
    float*    g_fc2T = (float*)A(65536);
    float*    g_savT = (float*)A(65536);
    float*    g_satT = (float*)A(65536);
    float*    g_sqkT = (float*)A(16384);

    float* bn1s = g_stats;
    float* bn2s = g_stats + 256;

    // dead-buffer reuse for SA partials (all prior readers complete in stream order):
    // g_q..g_res = 4 contiguous 8MB buffers -> 32 MB unscaled PV partials
    // g_res2 (free after bn1_apply) -> 256 KB colsum partials
    float* g_part   = g_q;
    float* g_cspart = g_res2;

    hipMemsetAsync(g_stats, 0, (size_t)512*4, stream);

    prep_kernel<<<592, 256, 0, stream>>>(fb2w, fg1w, fg2w, g_wpk,
                                         wq, wk, wv, fc2w, savw, satw, saqk,
                                         g_wqT, g_wkT, g_wvT, g_fc2T, g_savT, g_satT, g_sqkT);

    knn_kernel<<<1024, 256, 0, stream>>>(feat, g_idx);
    x1_kernel<<<8192, 256, 0, stream>>>(feat, fc1w, fc1b, g_x1);
    qkv_kernel<<<1024, 256, 0, stream>>>(g_x1, g_wqT, g_wkT, g_wvT, g_q, g_k1, g_v1);
    attn_kernel<<<4096, 256, 0, stream>>>(feat, g_idx, g_q, g_k1, g_v1, g_wpk,
                                          fb1w, fb1b, fb2b, fg1b, fg2b, out1, g_res);
    lin_kernel<<<1024, 256, 0, stream>>>(g_res, g_fc2T, fc2b, g_res2);
    bn_stats_kernel<<<512, 256, 0, stream>>>(g_res2, bn1s);
    bn1_apply_kernel<<<8192, 256, 0, stream>>>(g_res2, g_x1, bn1s, bng, bnb, g_sres);
    l5_kernel<<<1024, 256, 0, stream>>>(g_sres, g_savT, savb, g_sqkT, g_xvt_pk, g_xqk_pk);
    sa_stats_kernel<<<1024, 256, 0, stream>>>(g_xqk_pk, g_rm, g_rs);
    sa_xr_part_kernel<<<512*NSPLIT, 256, 0, stream>>>(g_xqk_pk, g_xvt_pk, g_rm, g_rs, g_part, g_cspart);
    sa_combine_kernel<<<8192, 256, 0, stream>>>(g_part, g_cspart, g_xr);
    l6_kernel<<<1024, 256, 0, stream>>>(g_sres, g_xr, g_satT, satb, g_xr2);
    bn_stats_kernel<<<512, 256, 0, stream>>>(g_xr2, bn2s);
    final_kernel<<<8192, 256, 0, stream>>>(g_sres, g_xr2, bn2s, sabng, sabnb, out0);
}

// Round 12
// 753.968 us; speedup vs baseline: 1.0152x; 1.0152x over previous
//
#include <hip/hip_runtime.h>

#define NPTS 16384   // B*N = 8*2048
#define NB 2048
#define KNN 20

typedef __attribute__((ext_vector_type(4))) float f32x4;
typedef __attribute__((ext_vector_type(8))) short short8;

union U4S8 { uint4 q; short8 s; };
union W4   { unsigned u[4]; short8 s; };

__device__ __forceinline__ unsigned bf16_rne(float v){
    unsigned u = __float_as_uint(v);
    return (u + 0x7fffu + ((u>>16)&1u)) >> 16;
}
// hw pack: low16 = bf16_rne(a), high16 = bf16_rne(b)
__device__ __forceinline__ unsigned cvt_pk_bf16(float a, float b){
    unsigned r;
    asm("v_cvt_pk_bf16_f32 %0, %1, %2" : "=v"(r) : "v"(a), "v"(b));
    return r;
}
// pack fp32 -> (hi bf16) | (lo bf16 << 16), hi+lo ~= v to ~2^-17 rel (value-identical to old bit-math)
__device__ __forceinline__ unsigned pack_hl(float v){
    unsigned h = cvt_pk_bf16(v, v);
    float r = v - __uint_as_float(h << 16);
    unsigned l = cvt_pk_bf16(r, r);
    return __builtin_amdgcn_perm(l, h, 0x05040100u);   // [h.b0,h.b1,l.b0,l.b1]
}
// pack a PAIR: h2 = hi(v0)|hi(v1)<<16, l2 = lo(v0)|lo(v1)<<16
__device__ __forceinline__ void pack2(float v0, float v1, unsigned& h2, unsigned& l2){
    h2 = cvt_pk_bf16(v0, v1);
    float r0 = v0 - __uint_as_float(h2 << 16);
    float r1 = v1 - __uint_as_float(h2 & 0xffff0000u);
    l2 = cvt_pk_bf16(r0, r1);
}
// split 8 packed (hi|lo<<16) words into hi/lo bf16x8 fragments
__device__ __forceinline__ void split_hl(uint4 w0, uint4 w1, short8& hi, short8& lo){
    W4 h, l;
    h.u[0] = __builtin_amdgcn_perm(w0.y, w0.x, 0x05040100u);
    l.u[0] = __builtin_amdgcn_perm(w0.y, w0.x, 0x07060302u);
    h.u[1] = __builtin_amdgcn_perm(w0.w, w0.z, 0x05040100u);
    l.u[1] = __builtin_amdgcn_perm(w0.w, w0.z, 0x07060302u);
    h.u[2] = __builtin_amdgcn_perm(w1.y, w1.x, 0x05040100u);
    l.u[2] = __builtin_amdgcn_perm(w1.y, w1.x, 0x07060302u);
    h.u[3] = __builtin_amdgcn_perm(w1.w, w1.z, 0x05040100u);
    l.u[3] = __builtin_amdgcn_perm(w1.w, w1.z, 0x07060302u);
    hi = h.s; lo = l.s;
}
// fp32-like product via 3 bf16 MFMAs (fixed order -> deterministic across kernels)
__device__ __forceinline__ f32x4 e3_mfma(short8 Ah, short8 Al, short8 Bh, short8 Bl){
    f32x4 acc = (f32x4){0.f,0.f,0.f,0.f};
    acc = __builtin_amdgcn_mfma_f32_16x16x32_bf16(Al, Bh, acc, 0,0,0);
    acc = __builtin_amdgcn_mfma_f32_16x16x32_bf16(Ah, Bl, acc, 0,0,0);
    acc = __builtin_amdgcn_mfma_f32_16x16x32_bf16(Ah, Bh, acc, 0,0,0);
    return acc;
}

// ---------------- merged prep: pack_bfrag (3x) + 6x transpose128 + 1x transpose32 ----------------
__global__ void prep_kernel(const float* w0, const float* w1, const float* w2, unsigned short* wpk,
                            const float* wq, const float* wk, const float* wv, const float* fc2w,
                            const float* savw, const float* satw, const float* saqk,
                            float* wqT, float* wkT, float* wvT, float* fc2T, float* savT, float* satT,
                            float* sqkT){
    int gid = blockIdx.x*256 + threadIdx.x;
    if (gid < 49152){
        int m = gid >> 14, r = gid & 16383;
        const float* W = (m==0)?w0:(m==1)?w1:w2;
        int e = r & 7, lane = (r>>3) & 63, ks = (r>>9)&3, ct = r>>11;
        int c = ct*16 + (lane&15), j = ks*32 + (lane>>4)*8 + e;
        wpk[gid] = (unsigned short)bf16_rne(W[c*128 + j]);
    } else if (gid < 147456){
        int t = gid - 49152;
        int m = t >> 14, r = t & 16383;
        const float* src = (m==0)?wq:(m==1)?wk:(m==2)?wv:(m==3)?fc2w:(m==4)?savw:satw;
        float* dst = (m==0)?wqT:(m==1)?wkT:(m==2)?wvT:(m==3)?fc2T:(m==4)?savT:satT;
        int j = r >> 7, c = r & 127;
        dst[r] = src[c*128 + j];
    } else {
        int r = gid - 147456;   // 4096 elems: sqkT[j*32+c] = saqk[c*128+j]
        int j = r >> 5, c = r & 31;
        sqkT[r] = saqk[c*128 + j];
    }
}

// ---------------- kNN ----------------
// Sortable-key argsort; see round-2 notes. Keys unique -> no tie handling.
__global__ __launch_bounds__(256) void knn_kernel(const float* feat, int* g_idx){
    __shared__ float sx[2048], sy[2048], sz[2048];
    __shared__ int swin[16*20];
    int tid = threadIdx.x;
    int p0 = blockIdx.x * 16;
    int b = p0 >> 11;
    const float* fb = feat + b*3*2048;
    for (int i = tid; i < 2048; i += 256){ sx[i]=fb[i]; sy[i]=fb[2048+i]; sz[i]=fb[4096+i]; }
    __syncthreads();

    int chunk = tid & 15, pl = tid >> 4;          // 16 points/block, 16 chunks each
    int n = (p0 + pl) & 2047;
    double xi = sx[n], yi = sy[n], zi = sz[n];

    const double SENT = __longlong_as_double(0x7FE0000000000000ll);  // 2^1023, > any key
    double val[20];
#pragma unroll
    for (int k=0;k<20;k++) val[k] = SENT;

    int base = chunk*128;
    for (int ii=0; ii<128; ii++){
        int i = (ii + (chunk<<1)) & 127;
        int j = base + i;
        double dx = (double)sx[j]-xi, dy = (double)sy[j]-yi, dz = (double)sz[j]-zi;
        double d2 = dx*dx + dy*dy + dz*dz;
        long long kb = ((__double_as_longlong(d2) & ~2047ll) | (long long)j) + (1ll<<61);
        double key = __longlong_as_double(kb);
        // branchless sorted insert (ascending), dep depth 2
#pragma unroll
        for (int s=19; s>=1; s--)
            val[s] = fmax(val[s-1], fmin(val[s], key));
        val[0] = fmin(val[0], key);
    }

    // merge 16 sorted per-lane lists (consecutive lanes) via in-wave min-reduce
    for (int kk=0; kk<20; kk++){
        double h = val[0];
        h = fmin(h, __shfl_xor(h, 1));
        h = fmin(h, __shfl_xor(h, 2));
        h = fmin(h, __shfl_xor(h, 4));
        h = fmin(h, __shfl_xor(h, 8));
        if (val[0] == h){        // exactly one lane wins (keys unique; SENT never wins)
            swin[pl*20 + kk] = (int)(__double_as_longlong(h) & 2047ll);
#pragma unroll
            for (int s=0;s<19;s++) val[s] = val[s+1];
            val[19] = SENT;
        }
    }
    __syncthreads();
    for (int t = tid; t < 320; t += 256)
        g_idx[p0*20 + t] = swin[t];
}

// ---------------- q/k/v with fused x1 ----------------
// v2 (round 12): x1 computed in-stage from feat (3 FMAs vs an 8MB x1 load) and
// written out for bn1_apply. Eliminates x1_kernel + qkv's 8MB x1 read.
__global__ __launch_bounds__(256) void qkv_kernel(const float* feat, const float* fc1w, const float* fc1b,
                                                  const float* wqT, const float* wkT, const float* wvT,
                                                  float* x1, float* q, float* k1, float* v1){
    __shared__ float sx[16][128];
    int tid = threadIdx.x;
    int p0 = blockIdx.x * 16;
    int b = p0 >> 11;
    const float* fb = feat + b*6144;
    for (int t = tid; t < 2048; t += 256){
        int pr = t >> 7, c = t & 127;
        int n = (p0 + pr) & 2047;
        float v = fc1b[c] + fc1w[c*3+0]*fb[n] + fc1w[c*3+1]*fb[2048+n] + fc1w[c*3+2]*fb[4096+n];
        sx[pr][c] = v;
        x1[(p0+pr)*128 + c] = v;
    }
    __syncthreads();
    int cg = tid & 31, pg = tid >> 5, c0 = cg*4;
    float aq[2][4] = {{0,0,0,0},{0,0,0,0}};
    float ak[2][4] = {{0,0,0,0},{0,0,0,0}};
    float av[2][4] = {{0,0,0,0},{0,0,0,0}};
    for (int j=0;j<128;j++){
        float xa = sx[pg][j], xb = sx[pg+8][j];
        float4 wq4 = *(const float4*)&wqT[j*128 + c0];
        float4 wk4 = *(const float4*)&wkT[j*128 + c0];
        float4 wv4 = *(const float4*)&wvT[j*128 + c0];
        const float* wqp = &wq4.x; const float* wkp = &wk4.x; const float* wvp = &wv4.x;
#pragma unroll
        for (int ci=0; ci<4; ci++){
            aq[0][ci] += wqp[ci]*xa; aq[1][ci] += wqp[ci]*xb;
            ak[0][ci] += wkp[ci]*xa; ak[1][ci] += wkp[ci]*xb;
            av[0][ci] += wvp[ci]*xa; av[1][ci] += wvp[ci]*xb;
        }
    }
#pragma unroll
    for (int pp=0; pp<2; pp++){
        int p = p0 + pg + pp*8;
        *(float4*)&q [p*128 + c0] = make_float4(aq[pp][0],aq[pp][1],aq[pp][2],aq[pp][3]);
        *(float4*)&k1[p*128 + c0] = make_float4(ak[pp][0],ak[pp][1],ak[pp][2],ak[pp][3]);
        *(float4*)&v1[p*128 + c0] = make_float4(av[pp][0],av[pp][1],av[pp][2],av[pp][3]);
    }
}

// ---------------- fused MFMA edge/attention kernel ----------------
// Dual-plane LDS (bufH/bufL bf16 shorts): A-frags read directly as short8.
// Round-8 epilogue kept verbatim (round-9 at->LDS staging regressed: HBM at 24%
// was not the constraint; the extra barrier+LDS round-trip added stalls).
#define ASTR 136   // shorts per row; mult of 8 (16B-aligned short8 reads)
__device__ __forceinline__ void stage_gemm(const unsigned short* bH, const unsigned short* bL,
                                           const unsigned short* wb, int lane, int ct0, f32x4 acc[5][2]){
    short8 bf[2][4];
#pragma unroll
    for (int ci=0; ci<2; ci++)
#pragma unroll
    for (int ks=0; ks<4; ks++){
        U4S8 u; u.q = *(const uint4*)(wb + ((ct0+ci)*4 + ks)*512 + lane*8);
        bf[ci][ks] = u.s;
    }
#pragma unroll
    for (int rt=0; rt<5; rt++)
#pragma unroll
    for (int ci=0; ci<2; ci++)
        acc[rt][ci] = (f32x4){0.f,0.f,0.f,0.f};
    int abase = (lane&15)*ASTR + (lane>>4)*8;
#pragma unroll
    for (int rt=0; rt<5; rt++){
#pragma unroll
        for (int ks=0; ks<4; ks++){
            int off = rt*16*ASTR + ks*32 + abase;
            short8 hi = *(const short8*)(bH + off);
            short8 lo = *(const short8*)(bL + off);
#pragma unroll
            for (int ci=0; ci<2; ci++){
                acc[rt][ci] = __builtin_amdgcn_mfma_f32_16x16x32_bf16(hi, bf[ci][ks], acc[rt][ci], 0,0,0);
                acc[rt][ci] = __builtin_amdgcn_mfma_f32_16x16x32_bf16(lo, bf[ci][ks], acc[rt][ci], 0,0,0);
            }
        }
    }
}

// store 4 packed pair-words (from acc) into the two planes at rows r0..r0+3, col
__device__ __forceinline__ void store4(unsigned short* bH, unsigned short* bL,
                                       int r0, int col, unsigned h2, unsigned l2, unsigned h3, unsigned l3){
    bH[(r0+0)*ASTR + col] = (unsigned short)h2;        bL[(r0+0)*ASTR + col] = (unsigned short)l2;
    bH[(r0+1)*ASTR + col] = (unsigned short)(h2>>16);  bL[(r0+1)*ASTR + col] = (unsigned short)(l2>>16);
    bH[(r0+2)*ASTR + col] = (unsigned short)h3;        bL[(r0+2)*ASTR + col] = (unsigned short)l3;
    bH[(r0+3)*ASTR + col] = (unsigned short)(h3>>16);  bL[(r0+3)*ASTR + col] = (unsigned short)(l3>>16);
}

__global__ __launch_bounds__(256, 3) void attn_kernel(
        const float* feat, const int* g_idx, const float* g_q, const float* g_k1, const float* g_v1,
        const unsigned short* wpk,
        const float* fb1w, const float* fb1b, const float* fb2b, const float* fg1b, const float* fg2b,
        float* g_attn, float* g_res){
    __shared__ __align__(16) unsigned short bufH[80*ASTR];   // 21760 B
    __shared__ __align__(16) unsigned short bufL[80*ASTR];   // 21760 B
    __shared__ float sh_q[512];
    __shared__ float sh_e[80*6];
    __shared__ int   sh_ix[80];
    int tid = threadIdx.x;
    int lane = tid & 63, wave = tid >> 6;
    // T1 XCD swizzle: batch == XCD id -> each XCD's L2 holds only its batch's k1/v1/q
    int bidx = blockIdx.x;
    int blk = ((bidx & 7) << 9) | (bidx >> 3);
    int gp0 = blk * 4;
    int b = gp0 >> 11;
    size_t kvbase = (size_t)b*2048*128;

    sh_q[tid]     = g_q[gp0*128 + tid];
    sh_q[tid+256] = g_q[gp0*128 + tid + 256];
    if (tid < 80){
        int r = tid;
        int nb = g_idx[gp0*20 + r];
        sh_ix[r] = nb;
        int p = (r*205) >> 12;
        int n = (gp0 & 2047) + p;
        const float* fbp = feat + b*6144;
        float cx = fbp[n], cy = fbp[2048+n], cz = fbp[4096+n];
        float nx = fbp[nb], ny = fbp[2048+nb], nz = fbp[4096+nb];
        sh_e[r*6+0] = nx-cx; sh_e[r*6+1] = ny-cy; sh_e[r*6+2] = nz-cz;
        sh_e[r*6+3] = cx;    sh_e[r*6+4] = cy;    sh_e[r*6+5] = cz;
    }
    __syncthreads();

    {
        int c = tid & 127, rh = tid >> 7;
        float w0=fb1w[c*6+0], w1=fb1w[c*6+1], w2=fb1w[c*6+2], w3=fb1w[c*6+3], w4=fb1w[c*6+4], w5=fb1w[c*6+5];
        float bb = fb1b[c];
#pragma unroll
        for (int t=0; t<20; t++){
            int r0 = t*4 + rh, r1 = r0 + 2;
            const float* e0 = &sh_e[r0*6];
            const float* e1 = &sh_e[r1*6];
            float v0 = fmaxf(bb + w0*e0[0]+w1*e0[1]+w2*e0[2]+w3*e0[3]+w4*e0[4]+w5*e0[5], 0.f);
            float v1 = fmaxf(bb + w0*e1[0]+w1*e1[1]+w2*e1[2]+w3*e1[3]+w4*e1[4]+w5*e1[5], 0.f);
            unsigned h2, l2; pack2(v0, v1, h2, l2);
            bufH[r0*ASTR + c] = (unsigned short)h2;       bufL[r0*ASTR + c] = (unsigned short)l2;
            bufH[r1*ASTR + c] = (unsigned short)(h2>>16); bufL[r1*ASTR + c] = (unsigned short)(l2>>16);
        }
    }
    __syncthreads();

    int ct0 = wave*2;
    int colA = ct0*16 + (lane&15);
    int colB = colA + 16;
    int quad = lane >> 4;
    f32x4 acc[5][2];
    float kfr[5][2][4];   // stage-1 edge features, register-resident

    stage_gemm(bufH, bufL, wpk, lane, ct0, acc);
    {
        float bA = fb2b[colA], bB = fb2b[colB];
#pragma unroll
        for (int rt=0; rt<5; rt++)
#pragma unroll
        for (int ci=0; ci<2; ci++){
            int col = ci ? colB : colA;
            float bias = ci ? bB : bA;
            float ain[4];
#pragma unroll
            for (int reg=0; reg<4; reg++){
                int row = rt*16 + quad*4 + reg;
                float kf = acc[rt][ci][reg] + bias;
                kfr[rt][ci][reg] = kf;
                int p = (row*205)>>12;
                int nb = sh_ix[row];
                float kg = g_k1[kvbase + (size_t)nb*128 + col];
                ain[reg] = sh_q[p*128 + col] - kg + kf;
            }
            unsigned h2,l2,h3,l3;
            pack2(ain[0], ain[1], h2, l2);
            pack2(ain[2], ain[3], h3, l3);
            acc[rt][ci][0] = __uint_as_float(h2); acc[rt][ci][1] = __uint_as_float(l2);
            acc[rt][ci][2] = __uint_as_float(h3); acc[rt][ci][3] = __uint_as_float(l3);
        }
    }
    __syncthreads();
#pragma unroll
    for (int rt=0; rt<5; rt++)
#pragma unroll
    for (int ci=0; ci<2; ci++)
        store4(bufH, bufL, rt*16 + quad*4, ci ? colB : colA,
               __float_as_uint(acc[rt][ci][0]), __float_as_uint(acc[rt][ci][1]),
               __float_as_uint(acc[rt][ci][2]), __float_as_uint(acc[rt][ci][3]));
    __syncthreads();

    stage_gemm(bufH, bufL, wpk + 16384, lane, ct0, acc);
    {
        float bA = fg1b[colA], bB = fg1b[colB];
#pragma unroll
        for (int rt=0; rt<5; rt++)
#pragma unroll
        for (int ci=0; ci<2; ci++){
            float bias = ci ? bB : bA;
            float v0 = fmaxf(acc[rt][ci][0] + bias, 0.f);
            float v1 = fmaxf(acc[rt][ci][1] + bias, 0.f);
            float v2 = fmaxf(acc[rt][ci][2] + bias, 0.f);
            float v3 = fmaxf(acc[rt][ci][3] + bias, 0.f);
            unsigned h2,l2,h3,l3;
            pack2(v0, v1, h2, l2);
            pack2(v2, v3, h3, l3);
            acc[rt][ci][0] = __uint_as_float(h2); acc[rt][ci][1] = __uint_as_float(l2);
            acc[rt][ci][2] = __uint_as_float(h3); acc[rt][ci][3] = __uint_as_float(l3);
        }
    }
    __syncthreads();
#pragma unroll
    for (int rt=0; rt<5; rt++)
#pragma unroll
    for (int ci=0; ci<2; ci++)
        store4(bufH, bufL, rt*16 + quad*4, ci ? colB : colA,
               __float_as_uint(acc[rt][ci][0]), __float_as_uint(acc[rt][ci][1]),
               __float_as_uint(acc[rt][ci][2]), __float_as_uint(acc[rt][ci][3]));
    __syncthreads();

    stage_gemm(bufH, bufL, wpk + 32768, lane, ct0, acc);
    // fused: bias + log-softmax(over k) in-register + at write + res accumulation.
    {
        const float SCALE = 0.08838834764831845f;
        const float NEGF  = -3e38f;
        float bA = fg2b[colA], bB = fg2b[colB];
#pragma unroll
        for (int ci=0; ci<2; ci++){
            int col = ci ? colB : colA;
            float bias = ci ? bB : bA;
            float lm[5];
#pragma unroll
            for (int rt=0; rt<5; rt++){
#pragma unroll
                for (int reg=0; reg<4; reg++)
                    acc[rt][ci][reg] = (acc[rt][ci][reg] + bias) * SCALE;
                lm[rt] = fmaxf(fmaxf(acc[rt][ci][0], acc[rt][ci][1]), fmaxf(acc[rt][ci][2], acc[rt][ci][3]));
            }
            // per-p max: p appears at rt=p (if p<=quad) and rt=p+1 (if p>=quad)
            float m[4];
#pragma unroll
            for (int j=0; j<4; j++){
                float c1 = (j<=quad) ? lm[j]   : NEGF;
                float c2 = (j>=quad) ? lm[j+1] : NEGF;
                m[j] = fmaxf(c1, c2);
                m[j] = fmaxf(m[j], __shfl_xor(m[j], 16));
                m[j] = fmaxf(m[j], __shfl_xor(m[j], 32));
            }
            // per-rt broadcast of m[p_rt]: p_rt = rt - (rt > quad)
            float mp[5];
            mp[0] = m[0];
            mp[1] = (1<=quad) ? m[1] : m[0];
            mp[2] = (2<=quad) ? m[2] : m[1];
            mp[3] = (3<=quad) ? m[3] : m[2];
            mp[4] = m[3];
            float ls[5];
#pragma unroll
            for (int rt=0; rt<5; rt++){
                float e0 = expf(acc[rt][ci][0] - mp[rt]);
                float e1 = expf(acc[rt][ci][1] - mp[rt]);
                float e2 = expf(acc[rt][ci][2] - mp[rt]);
                float e3 = expf(acc[rt][ci][3] - mp[rt]);
                ls[rt] = (e0 + e1) + (e2 + e3);
            }
            float L[4];
#pragma unroll
            for (int j=0; j<4; j++){
                float c1 = (j<=quad) ? ls[j]   : 0.f;
                float c2 = (j>=quad) ? ls[j+1] : 0.f;
                float S = c1 + c2;
                S += __shfl_xor(S, 16);
                S += __shfl_xor(S, 32);
                L[j] = m[j] + logf(S);
            }
            float Lp[5];
            Lp[0] = L[0];
            Lp[1] = (1<=quad) ? L[1] : L[0];
            Lp[2] = (2<=quad) ? L[2] : L[1];
            Lp[3] = (3<=quad) ? L[3] : L[2];
            Lp[4] = L[3];
            // at write + res partials
            float pv[5];
#pragma unroll
            for (int rt=0; rt<5; rt++){
                float pacc = 0.f;
#pragma unroll
                for (int reg=0; reg<4; reg++){
                    int row = rt*16 + quad*4 + reg;
                    float at = acc[rt][ci][reg] - Lp[rt];
                    g_attn[(size_t)(gp0*20 + row)*128 + col] = at;
                    int nb = sh_ix[row];
                    float vv = g_v1[kvbase + (size_t)nb*128 + col];
                    pacc += at * (vv + kfr[rt][ci][reg]);
                }
                pv[rt] = pacc;
            }
#pragma unroll
            for (int j=0; j<4; j++){
                float c1 = (j<=quad) ? pv[j]   : 0.f;
                float c2 = (j>=quad) ? pv[j+1] : 0.f;
                float P = c1 + c2;
                P += __shfl_xor(P, 16);
                P += __shfl_xor(P, 32);
                pv[j] = P;   // reuse: pv[0..3] now hold full res for p=j
            }
            float rv = (quad==0) ? pv[0] : (quad==1) ? pv[1] : (quad==2) ? pv[2] : pv[3];
            g_res[(size_t)(gp0 + quad)*128 + col] = rv;
        }
    }
}

// ---------------- generic per-point linear (128->128) ----------------
__global__ __launch_bounds__(256) void lin_kernel(const float* X, const float* WT, const float* bias, float* Y){
    __shared__ float sx[16][128];
    int tid = threadIdx.x;
    int p0 = blockIdx.x * 16;
    for (int t = tid; t < 2048; t += 256) sx[t>>7][t&127] = X[p0*128 + t];
    __syncthreads();
    int cg = tid & 31, pg = tid >> 5, c0 = cg*4;
    float a[2][4] = {{0,0,0,0},{0,0,0,0}};
    for (int j=0;j<128;j++){
        float xa = sx[pg][j], xb = sx[pg+8][j];
        float4 w4 = *(const float4*)&WT[j*128 + c0];
        const float* wp = &w4.x;
#pragma unroll
        for (int ci=0;ci<4;ci++){ a[0][ci] += wp[ci]*xa; a[1][ci] += wp[ci]*xb; }
    }
    float4 bv = *(const float4*)&bias[c0];
    const float* bp = &bv.x;
#pragma unroll
    for (int pp=0;pp<2;pp++){
        int p = p0 + pg + pp*8;
        *(float4*)&Y[p*128+c0] = make_float4(a[pp][0]+bp[0], a[pp][1]+bp[1], a[pp][2]+bp[2], a[pp][3]+bp[3]);
    }
}

// l6 v2 (round 12): sa_combine fused into staging — sx = sres - xr where
// xr = (sum of 4 part planes) / (1e-9 + sum of 4 cspart planes). Identical op
// order to the old sa_combine kernel -> bit-identical values; saves the 8MB
// xr write + 8MB xr read and one kernel.
__global__ __launch_bounds__(256) void l6_kernel(const float* Xa, const float* part, const float* cspart,
                                                 const float* WT, const float* bias, float* Y){
    __shared__ float sx[16][128];
    int tid = threadIdx.x;
    int p0 = blockIdx.x * 16;
    for (int t = tid; t < 2048; t += 256){
        int gid = p0*128 + t;
        int bm = gid >> 7;
        float cs = cspart[bm] + cspart[bm+16384] + cspart[bm+2*16384] + cspart[bm+3*16384];
        float v  = part[gid] + part[gid+2097152] + part[gid+2*2097152] + part[gid+3*2097152];
        float xr = v * (1.0f/(1e-9f + cs));
        sx[t>>7][t&127] = Xa[gid] - xr;
    }
    __syncthreads();
    int cg = tid & 31, pg = tid >> 5, c0 = cg*4;
    float a[2][4] = {{0,0,0,0},{0,0,0,0}};
    for (int j=0;j<128;j++){
        float xa = sx[pg][j], xb = sx[pg+8][j];
        float4 w4 = *(const float4*)&WT[j*128 + c0];
        const float* wp = &w4.x;
#pragma unroll
        for (int ci=0;ci<4;ci++){ a[0][ci] += wp[ci]*xa; a[1][ci] += wp[ci]*xb; }
    }
    float4 bv = *(const float4*)&bias[c0];
    const float* bp = &bv.x;
#pragma unroll
    for (int pp=0;pp<2;pp++){
        int p = p0 + pg + pp*8;
        *(float4*)&Y[p*128+c0] = make_float4(a[pp][0]+bp[0], a[pp][1]+bp[1], a[pp][2]+bp[2], a[pp][3]+bp[3]);
    }
}

// l5: xv = sa_v @ sres + b  -> packed hi/lo bf16, layout [b][nchunk32][c128][n32]
//     xqk = sa_qk @ sres    -> packed hi/lo bf16, layout [n][32]
__global__ __launch_bounds__(256) void l5_kernel(const float* X, const float* WvT, const float* vb,
                                                 const float* WqkT, unsigned* xvt_pk, unsigned* xqk_pk){
    __shared__ float sx[16][128];
    int tid = threadIdx.x;
    int p0 = blockIdx.x * 16;
    for (int t = tid; t < 2048; t += 256) sx[t>>7][t&127] = X[p0*128 + t];
    __syncthreads();
    int cg = tid & 31, pg = tid >> 5, c0 = cg*4;
    {
        float a[2][4] = {{0,0,0,0},{0,0,0,0}};
        for (int j=0;j<128;j++){
            float xa = sx[pg][j], xb = sx[pg+8][j];
            float4 w4 = *(const float4*)&WvT[j*128 + c0];
            const float* wp = &w4.x;
#pragma unroll
            for (int ci=0;ci<4;ci++){ a[0][ci] += wp[ci]*xa; a[1][ci] += wp[ci]*xb; }
        }
        float4 bv = *(const float4*)&vb[c0];
        const float* bp = &bv.x;
#pragma unroll
        for (int pp=0;pp<2;pp++){
            int p = p0 + pg + pp*8;
            int bb = p >> 11, n = p & 2047;
            unsigned* dst = xvt_pk + ((size_t)(bb*64 + (n>>5)))*4096 + (n&31);
#pragma unroll
            for (int ci=0;ci<4;ci++) dst[(c0+ci)*32] = pack_hl(a[pp][ci] + bp[ci]);
        }
    }
    if (cg < 8){
        int cq = cg*4;
        float a[2][4] = {{0,0,0,0},{0,0,0,0}};
        for (int j=0;j<128;j++){
            float xa = sx[pg][j], xb = sx[pg+8][j];
            float4 w4 = *(const float4*)&WqkT[j*32 + cq];
            const float* wp = &w4.x;
#pragma unroll
            for (int ci=0;ci<4;ci++){ a[0][ci] += wp[ci]*xa; a[1][ci] += wp[ci]*xb; }
        }
#pragma unroll
        for (int pp=0;pp<2;pp++){
            int p = p0 + pg + pp*8;
            uint4 w;
            w.x = pack_hl(a[pp][0]); w.y = pack_hl(a[pp][1]);
            w.z = pack_hl(a[pp][2]); w.w = pack_hl(a[pp][3]);
            *(uint4*)&xqk_pk[p*32 + cq] = w;
        }
    }
}

// ---------------- batchnorm ----------------
__global__ void bn_stats_kernel(const float* X, float* sums){
    int tid = threadIdx.x;
    int c = tid & 127, half = tid >> 7;
    int r0 = blockIdx.x*32 + half*16;
    float s = 0.f, sq = 0.f;
    for (int r = r0; r < r0+16; r++){
        float v = X[r*128 + c];
        s += v; sq += v*v;
    }
    atomicAdd(&sums[c], s);
    atomicAdd(&sums[128+c], sq);
}

__global__ void bn1_apply_kernel(const float* res2, const float* x1, const float* sums,
                                 const float* g, const float* beta, float* sres){
    int gid = blockIdx.x*256 + threadIdx.x;
    int c = gid & 127;
    float mu = sums[c] * (1.0f/16384.f);
    float var = sums[128+c] * (1.0f/16384.f) - mu*mu;
    float inv = 1.0f / sqrtf(var + 1e-5f);
    float y = g[c]*(res2[gid]-mu)*inv + beta[c];
    sres[gid] = fmaxf(y, 0.f) + x1[gid];
}

__global__ void final_kernel(const float* sres, const float* xr2, const float* sums,
                             const float* g, const float* beta, float* out0){
    int gid = blockIdx.x*256 + threadIdx.x;
    int c = gid & 127;
    float mu = sums[c] * (1.0f/16384.f);
    float var = sums[128+c] * (1.0f/16384.f) - mu*mu;
    float inv = 1.0f / sqrtf(var + 1e-5f);
    float y = g[c]*(xr2[gid]-mu)*inv + beta[c];
    out0[gid] = sres[gid] + fmaxf(y, 0.f);
}

// ---------------- SA pass A: row max (hi-only) + exp-sum (3-product) via MFMA ----------------
__global__ __launch_bounds__(256) void sa_stats_kernel(const unsigned* xqk_pk, float* rm, float* irs){
    __shared__ float sred[4][16];
    __shared__ float srm[16];
    int tid = threadIdx.x;
    int lane = tid & 63, wave = tid >> 6;
    int b = blockIdx.x & 7;                 // T1 XCD swizzle: batch == XCD id
    int i0 = (blockIdx.x >> 3) * 16;
    const unsigned* qb = xqk_pk + (size_t)b*2048*32;
    int quad = lane >> 4, l15 = lane & 15;
    const unsigned* ap = qb + (i0 + l15)*32 + quad*8;
    uint4 a0 = *(const uint4*)ap, a1 = *(const uint4*)(ap+4);
    short8 Ah, Al; split_hl(a0, a1, Ah, Al);

    int jt0 = wave*32;
    float m[4] = {-3e38f,-3e38f,-3e38f,-3e38f};
    for (int jt=jt0; jt<jt0+32; jt++){
        const unsigned* bp = qb + (jt*16 + l15)*32 + quad*8;
        uint4 b0 = *(const uint4*)bp, b1 = *(const uint4*)(bp+4);
        short8 Bh, Bl; split_hl(b0,b1,Bh,Bl);
        f32x4 e = (f32x4){0.f,0.f,0.f,0.f};
        e = __builtin_amdgcn_mfma_f32_16x16x32_bf16(Ah, Bh, e, 0,0,0);
#pragma unroll
        for (int r=0;r<4;r++) m[r] = fmaxf(m[r], e[r]);
    }
#pragma unroll
    for (int mk=1; mk<16; mk<<=1)
#pragma unroll
        for (int r=0;r<4;r++) m[r] = fmaxf(m[r], __shfl_xor(m[r], mk));
    if (l15 == 0){
#pragma unroll
        for (int r=0;r<4;r++) sred[wave][quad*4+r] = m[r];
    }
    __syncthreads();
    if (tid < 16)
        srm[tid] = fmaxf(fmaxf(sred[0][tid], sred[1][tid]), fmaxf(sred[2][tid], sred[3][tid]));
    __syncthreads();
    float mp[4];
#pragma unroll
    for (int r=0;r<4;r++) mp[r] = srm[quad*4+r];

    float s[4] = {0.f,0.f,0.f,0.f};
    for (int jt=jt0; jt<jt0+32; jt++){
        const unsigned* bp = qb + (jt*16 + l15)*32 + quad*8;
        uint4 b0 = *(const uint4*)bp, b1 = *(const uint4*)(bp+4);
        short8 Bh, Bl; split_hl(b0,b1,Bh,Bl);
        f32x4 e = e3_mfma(Ah,Al,Bh,Bl);
#pragma unroll
        for (int r=0;r<4;r++) s[r] += expf(e[r]-mp[r]);
    }
#pragma unroll
    for (int mk=1; mk<16; mk<<=1)
#pragma unroll
        for (int r=0;r<4;r++) s[r] += __shfl_xor(s[r], mk);
    __syncthreads();
    if (l15 == 0){
#pragma unroll
        for (int r=0;r<4;r++) sred[wave][quad*4+r] = s[r];
    }
    __syncthreads();
    if (tid < 16){
        float S = (sred[0][tid] + sred[1][tid]) + (sred[2][tid] + sred[3][tid]);
        rm[b*2048 + i0 + tid]  = srm[tid];
        irs[b*2048 + i0 + tid] = 1.0f/S;
    }
}

// ---------------- SA pass B: fused colsum + PV (flash-style), MFMA ----------------
// 4-way n-split for occupancy; NO register prefetch (round-3 spill lesson).
#define SXV_STR 36
#define ATT_STR 36
#define NSPLIT 4
__global__ __launch_bounds__(256) void sa_xr_part_kernel(const unsigned* xqk_pk, const unsigned* xvt_pk,
                                                         const float* rm, const float* irs,
                                                         float* part, float* cspart){
    __shared__ __align__(16) unsigned sxv[128*SXV_STR];   // 18432 B
    __shared__ __align__(16) unsigned attT[32*ATT_STR];   // 4608 B
    __shared__ float scs[2][2][16];
    int tid = threadIdx.x;
    int lane = tid & 63, wave = tid >> 6;
    int quad = lane >> 4, l15 = lane & 15;
    // T1 XCD swizzle: batch == XCD id (2048 = 8 x 256 blocks)
    int bid = blockIdx.x;
    int b   = bid & 7;
    int rest = bid >> 3;           // 0..255
    int ns  = rest >> 6;           // 0..3
    int mt  = rest & 63;           // 0..63
    int m0 = mt*32;
    int rt = wave >> 1, ct = wave & 1;
    const unsigned* qb = xqk_pk + (size_t)b*2048*32;

    // B-frags for this block's m-cols (energy), loaded once
    short8 Bmh, Bml;
    {
        const unsigned* bp = qb + (m0 + ct*16 + l15)*32 + quad*8;
        uint4 b0 = *(const uint4*)bp, b1 = *(const uint4*)(bp+4);
        split_hl(b0,b1,Bmh,Bml);
    }
    f32x4 acc[4];
#pragma unroll
    for (int cc=0;cc<4;cc++) acc[cc] = (f32x4){0.f,0.f,0.f,0.f};
    float cs_acc = 0.f;

    int ch0 = ns*16;
    for (int ci16=0; ci16<16; ci16++){
        int chunk = ch0 + ci16;
        int n0 = chunk*32;
        __syncthreads();   // prev PV reads done
        // stage xv chunk -> LDS (packed hi/lo), [c][n] stride SXV_STR
        const unsigned* src = xvt_pk + ((size_t)(b*64 + chunk))*4096;
#pragma unroll
        for (int it=0; it<4; it++){
            int u = tid + it*256;
            int c = u >> 3, part_ = u & 7;
            *(uint4*)&sxv[c*SXV_STR + part_*4] = *(const uint4*)(src + u*4);
        }
        // energy tile (rt, ct): rows n0+rt*16.., cols m0+ct*16..
        const unsigned* ap = qb + (n0 + rt*16 + l15)*32 + quad*8;
        uint4 a0 = *(const uint4*)ap, a1 = *(const uint4*)(ap+4);
        short8 Ah, Al; split_hl(a0,a1,Ah,Al);
        f32x4 e = e3_mfma(Ah,Al,Bmh,Bml);
        // att + colsum acc + write attT (packed hi/lo)
#pragma unroll
        for (int r=0;r<4;r++){
            int rowg = b*2048 + n0 + rt*16 + quad*4 + r;
            float att = expf(e[r] - rm[rowg]) * irs[rowg];
            cs_acc += att;
            attT[(ct*16+l15)*ATT_STR + rt*16 + quad*4 + r] = pack_hl(att);
        }
        __syncthreads();
        // PV: A = att^T (m-sub = ct), B = xv (c-subs rt*4..rt*4+3)
        const unsigned* arp = attT + (ct*16+l15)*ATT_STR + quad*8;
        uint4 aa0 = *(const uint4*)arp, aa1 = *(const uint4*)(arp+4);
        short8 Aph, Apl; split_hl(aa0,aa1,Aph,Apl);
#pragma unroll
        for (int cc=0; cc<4; cc++){
            int c0 = (rt*4 + cc)*16;
            const unsigned* xp = &sxv[(c0 + l15)*SXV_STR + quad*8];
            uint4 x0 = *(const uint4*)xp, x1 = *(const uint4*)(xp+4);
            short8 Xh, Xl; split_hl(x0,x1,Xh,Xl);
            acc[cc] = __builtin_amdgcn_mfma_f32_16x16x32_bf16(Apl, Xh, acc[cc], 0,0,0);
            acc[cc] = __builtin_amdgcn_mfma_f32_16x16x32_bf16(Aph, Xl, acc[cc], 0,0,0);
            acc[cc] = __builtin_amdgcn_mfma_f32_16x16x32_bf16(Aph, Xh, acc[cc], 0,0,0);
        }
    }
    // colsum partial: reduce across quads, combine rt halves
    cs_acc += __shfl_xor(cs_acc, 16);
    cs_acc += __shfl_xor(cs_acc, 32);
    if (lane < 16) scs[ct][rt][lane] = cs_acc;
    __syncthreads();
    if (tid < 32)
        cspart[(size_t)(ns*8 + b)*2048 + m0 + tid] = scs[tid>>4][0][tid&15] + scs[tid>>4][1][tid&15];
    // unscaled partial write: row m = m0+ct*16+quad*4+r, col = (rt*4+cc)*16+l15
#pragma unroll
    for (int cc=0; cc<4; cc++){
        int c0 = (rt*4 + cc)*16;
#pragma unroll
        for (int r=0;r<4;r++){
            int mloc = ct*16 + quad*4 + r;
            part[((size_t)(ns*8 + b)*2048 + m0 + mloc)*128 + c0 + l15] = acc[cc][r];
        }
    }
}

// ---------------- launch ----------------
extern "C" void kernel_launch(void* const* d_in, const int* in_sizes, int n_in,
                              void* d_out, int out_size, void* d_ws, size_t ws_size,
                              hipStream_t stream){
    (void)in_sizes; (void)n_in; (void)out_size; (void)ws_size;
    const float* feat = (const float*)d_in[0];
    const float* fc1w = (const float*)d_in[1];  const float* fc1b = (const float*)d_in[2];
    const float* fc2w = (const float*)d_in[3];  const float* fc2b = (const float*)d_in[4];
    const float* bng  = (const float*)d_in[5];  const float* bnb  = (const float*)d_in[6];
    const float* fb1w = (const float*)d_in[7];  const float* fb1b = (const float*)d_in[8];
    const float* fb2w = (const float*)d_in[9];  const float* fb2b = (const float*)d_in[10];
    const float* fg1w = (const float*)d_in[11]; const float* fg1b = (const float*)d_in[12];
    const float* fg2w = (const float*)d_in[13]; const float* fg2b = (const float*)d_in[14];
    const float* wq   = (const float*)d_in[15]; const float* wk   = (const float*)d_in[16];
    const float* wv   = (const float*)d_in[17];
    const float* saqk = (const float*)d_in[18];
    const float* savw = (const float*)d_in[19]; const float* savb = (const float*)d_in[20];
    const float* satw = (const float*)d_in[21]; const float* satb = (const float*)d_in[22];
    const float* sabng= (const float*)d_in[23]; const float* sabnb= (const float*)d_in[24];

    float* out0 = (float*)d_out;
    float* out1 = out0 + 2097152;

    char* ws = (char*)d_ws;
    size_t off = 0;
    auto A = [&](size_t bytes)->char*{
        char* r = ws + off;
        off = (off + bytes + 255) & ~(size_t)255;
        return r;
    };
    const size_t PBUF = (size_t)NPTS*128*4;   // 8 MB
    int*      g_idx  = (int*)A((size_t)NPTS*KNN*4);
    float*    g_x1   = (float*)A(PBUF);
    float*    g_q    = (float*)A(PBUF);
    float*    g_k1   = (float*)A(PBUF);
    float*    g_v1   = (float*)A(PBUF);
    float*    g_res  = (float*)A(PBUF);
    float*    g_res2 = (float*)A(PBUF);
    float*    g_sres = (float*)A(PBUF);
    float*    g_xr   = (float*)A(PBUF);
    float*    g_xr2  = (float*)A(PBUF);
    unsigned* g_xvt_pk = (unsigned*)A((size_t)NPTS*128*4);   // 8 MB packed
    unsigned* g_xqk_pk = (unsigned*)A((size_t)NPTS*32*4);    // 2 MB packed
    float*    g_rm   = (float*)A((size_t)NPTS*4);
    float*    g_rs   = (float*)A((size_t)NPTS*4);            // holds 1/rs
    float*    g_stats= (float*)A((size_t)512*4);             // bn1(256) bn2(256)
    unsigned short* g_wpk = (unsigned short*)A((size_t)3*16384*2);
    float*    g_wqT  = (float*)A(65536);
    float*    g_wkT  = (float*)A(65536);
    float*    g_wvT  = (float*)A(65536);
    float*    g_fc2T = (float*)A(65536);
    float*    g_savT = (float*)A(65536);
    float*    g_satT = (float*)A(65536);
    float*    g_sqkT = (float*)A(16384);

    float* bn1s = g_stats;
    float* bn2s = g_stats + 256;
    (void)g_xr;

    // dead-buffer reuse for SA partials (all prior readers complete in stream order):
    // g_q..g_res = 4 contiguous 8MB buffers -> 32 MB unscaled PV partials
    // g_res2 (free after bn1_apply) -> 256 KB colsum partials
    float* g_part   = g_q;
    float* g_cspart = g_res2;

    hipMemsetAsync(g_stats, 0, (size_t)512*4, stream);

    prep_kernel<<<592, 256, 0, stream>>>(fb2w, fg1w, fg2w, g_wpk,
                                         wq, wk, wv, fc2w, savw, satw, saqk,
                                         g_wqT, g_wkT, g_wvT, g_fc2T, g_savT, g_satT, g_sqkT);

    knn_kernel<<<1024, 256, 0, stream>>>(feat, g_idx);
    qkv_kernel<<<1024, 256, 0, stream>>>(feat, fc1w, fc1b, g_wqT, g_wkT, g_wvT, g_x1, g_q, g_k1, g_v1);
    attn_kernel<<<4096, 256, 0, stream>>>(feat, g_idx, g_q, g_k1, g_v1, g_wpk,
                                          fb1w, fb1b, fb2b, fg1b, fg2b, out1, g_res);
    lin_kernel<<<1024, 256, 0, stream>>>(g_res, g_fc2T, fc2b, g_res2);
    bn_stats_kernel<<<512, 256, 0, stream>>>(g_res2, bn1s);
    bn1_apply_kernel<<<8192, 256, 0, stream>>>(g_res2, g_x1, bn1s, bng, bnb, g_sres);
    l5_kernel<<<1024, 256, 0, stream>>>(g_sres, g_savT, savb, g_sqkT, g_xvt_pk, g_xqk_pk);
    sa_stats_kernel<<<1024, 256, 0, stream>>>(g_xqk_pk, g_rm, g_rs);
    sa_xr_part_kernel<<<512*NSPLIT, 256, 0, stream>>>(g_xqk_pk, g_xvt_pk, g_rm, g_rs, g_part, g_cspart);
    l6_kernel<<<1024, 256, 0, stream>>>(g_sres, g_part, g_cspart, g_satT, satb, g_xr2);
    bn_stats_kernel<<<512, 256, 0, stream>>>(g_xr2, bn2s);
    final_kernel<<<8192, 256, 0, stream>>>(g_sres, g_xr2, bn2s, sabng, sabnb, out0);
}